// Round 5
// baseline (91.358 us; speedup 1.0000x reference)
//
#include <hip/hip_runtime.h>

#define N_GENES 768
#define H 128
#define TI 48        // i-rows per block
#define TJ 16        // j-cols per block -> grid 16 x 48 = 768 blocks = 3 per CU
#define LDP 132      // f32 LDS row stride: +4 keeps 16B alignment, 2-way bank alias (free)
#define LDPH 136     // f16 LDS row stride in halves: 272B rows, 16B-aligned

typedef float    f2 __attribute__((ext_vector_type(2)));
typedef _Float16 h2 __attribute__((ext_vector_type(2)));
typedef _Float16 h8 __attribute__((ext_vector_type(8)));

// ---------------------------------------------------------------------------
// Kernel A (R2/R4-exact): per-gene projections, f64 accumulate -> AiB/Bjp
// bit-identical across rounds; f16 copies Yh/Xh; interleaved W2-diffs Wd.
// ---------------------------------------------------------------------------
__global__ __launch_bounds__(128) void grn_pre(
    const float* __restrict__ X, const float* __restrict__ W1,
    const float* __restrict__ b1, const float* __restrict__ Wb,
    const float* __restrict__ W2,
    float* __restrict__ AiB, float* __restrict__ Bjp, float* __restrict__ Wd,
    _Float16* __restrict__ Yh, _Float16* __restrict__ Xh)
{
    const int m  = threadIdx.x;       // 0..127
    const int g0 = blockIdx.x * 3;    // 256 blocks x 3 genes

    __shared__ float Xs[3][H];
    #pragma unroll
    for (int r = 0; r < 3; ++r) Xs[r][m] = X[(g0 + r) * H + m];
    __syncthreads();

    double aib[3] = {0, 0, 0}, bj[3] = {0, 0, 0}, y[3] = {0, 0, 0};
    const float4* W1a = (const float4*)(W1 + m * (2 * H));
    const float4* W1b = (const float4*)(W1 + m * (2 * H) + H);

    #pragma unroll 4
    for (int kq = 0; kq < H / 4; ++kq) {
        float4 wa = W1a[kq];
        float4 wb = W1b[kq];
        float wc[4];
        #pragma unroll
        for (int e = 0; e < 4; ++e) wc[e] = Wb[(kq * 4 + e) * H + m];
        const float* wae = &wa.x;
        const float* wbe = &wb.x;
        #pragma unroll
        for (int r = 0; r < 3; ++r) {
            float4 xr = *(const float4*)&Xs[r][kq * 4];
            const float* xe = &xr.x;
            #pragma unroll
            for (int e = 0; e < 4; ++e) {
                aib[r] += (double)xe[e] * (double)wae[e];
                bj[r]  += (double)xe[e] * (double)wbe[e];
                y[r]   += (double)xe[e] * (double)wc[e];
            }
        }
    }

    const double b1m = (double)b1[m];
    #pragma unroll
    for (int r = 0; r < 3; ++r) {
        AiB[(g0 + r) * H + m] = (float)(aib[r] + b1m);
        Bjp[(g0 + r) * H + m] = (float)bj[r];
        Yh [(g0 + r) * H + m] = (_Float16)(float)y[r];
        Xh [(g0 + r) * H + m] = (_Float16)Xs[r][m];
    }

    if (blockIdx.x == 0) {
        Wd[2 * m]     = W2[m] - W2[2 * H + m];  // u-weight: W2[0]-W2[2]
        Wd[2 * m + 1] = W2[m] - W2[H + m];      // v-weight: W2[0]-W2[1]
    }
}

// ---------------------------------------------------------------------------
// Kernel B: 768 blocks (3/CU -> 3 waves/SIMD), 256 threads, 48x16 tile,
// 3 pairs/thread (rows it+{0,16,32}, col jt). Col-side operands (Xh, Bjp)
// in LDS (~13 KB); row-side (Yh, AiB) via global L1/L2 broadcast loads
// (4 distinct rows/wave) on the VMEM pipe. Math bit-identical to R2/R4.
// ---------------------------------------------------------------------------
__global__ __launch_bounds__(256) void grn_main(
    const float* __restrict__ AiB, const float* __restrict__ Bjp,
    const _Float16* __restrict__ Yh, const _Float16* __restrict__ Xh,
    const float* __restrict__ Wd,  const float* __restrict__ b2,
    const float* __restrict__ bb,  float* __restrict__ out)
{
    const int gj = blockIdx.x % 48;
    const int gi = blockIdx.x / 48;
    const int tx = threadIdx.x;
    const int it = tx >> 4;   // 0..15 -> rows it+{0,16,32}
    const int jt = tx & 15;   // 0..15 -> col gj*16+jt

    __shared__ _Float16 sXh[TJ * LDPH];  // Xh col tile (4.3 KB)
    __shared__ float    sB [TJ * LDP];   // Bjp col tile (8.3 KB)

    // stage col tiles (coalesced; 256 threads)
    {
        int row = tx >> 4, c8 = tx & 15;          // 256 h8 chunks
        *(h8*)&sXh[row * LDPH + c8 * 8] =
            *(const h8*)&Xh[(gj * TJ + row) * H + c8 * 8];
        #pragma unroll
        for (int t = 0; t < 2; ++t) {
            int k  = tx + t * 256;                // 512 float4 chunks
            int r2 = k >> 5, c4 = k & 31;
            *(float4*)&sB[r2 * LDP + c4 * 4] =
                *(const float4*)&Bjp[(gj * TJ + r2) * H + c4 * 4];
        }
    }
    __syncthreads();

    // ---- phase 1: affinity, exact R2 accumulation order (q asc, p asc) ----
    float aff[3] = {0.0f, 0.0f, 0.0f};
    const _Float16* yRow = Yh + (gi * TI + it) * H;   // rows +0, +16H, +32H
    #pragma unroll 4
    for (int q = 0; q < H / 8; ++q) {
        h8 xv = *(const h8*)&sXh[jt * LDPH + q * 8];
        h8 yv[3];
        #pragma unroll
        for (int r = 0; r < 3; ++r) yv[r] = *(const h8*)(yRow + r * 16 * H + q * 8);
        #pragma unroll
        for (int r = 0; r < 3; ++r)
            #pragma unroll
            for (int p = 0; p < 4; ++p) {
                h2 a; a.x = yv[r][2*p]; a.y = yv[r][2*p+1];
                h2 b; b.x = xv[2*p];    b.y = xv[2*p+1];
#if __has_builtin(__builtin_amdgcn_fdot2)
                aff[r] = __builtin_amdgcn_fdot2(a, b, aff[r], false);
#else
                aff[r] = fmaf((float)a.x, (float)b.x, aff[r]);
                aff[r] = fmaf((float)a.y, (float)b.y, aff[r]);
#endif
            }
    }

    // ---- phase 2: u/v, exact R4 per-component pk-fma order ----
    const f2 uv0 = {b2[0] - b2[2], b2[0] - b2[1]};
    f2 uv[3] = {uv0, uv0, uv0};
    const float*  aRow = AiB + (gi * TI + it) * H;
    const float4* Wduv = (const float4*)Wd;

    const f2 zero2 = {0.0f, 0.0f};
    #pragma unroll 4
    for (int mq = 0; mq < H / 4; ++mq) {
        float4 wq0 = Wduv[2 * mq];        // uniform -> scalar load
        float4 wq1 = Wduv[2 * mq + 1];
        float4 bv  = *(const float4*)&sB[jt * LDP + mq * 4];
        f2 b01 = {bv.x, bv.y}, b23 = {bv.z, bv.w};
        #pragma unroll
        for (int r = 0; r < 3; ++r) {
            float4 av = *(const float4*)(aRow + r * 16 * H + mq * 4);
            f2 a01 = {av.x, av.y}, a23 = {av.z, av.w};
            f2 h01 = __builtin_elementwise_max(a01 + b01, zero2);
            f2 h23 = __builtin_elementwise_max(a23 + b23, zero2);
            f2 t = uv[r];
            t = (f2){h01.x, h01.x} * (f2){wq0.x, wq0.y} + t;   // m0
            t = (f2){h01.y, h01.y} * (f2){wq0.z, wq0.w} + t;   // m1
            t = (f2){h23.x, h23.x} * (f2){wq1.x, wq1.y} + t;   // m2
            t = (f2){h23.y, h23.y} * (f2){wq1.z, wq1.w} + t;   // m3
            uv[r] = t;
        }
    }

    // ---- epilogue ----
    const float bbv = bb[0];
    const int j = gj * TJ + jt;
    #pragma unroll
    for (int r = 0; r < 3; ++r) {
        const int i = gi * TI + it + 16 * r;
        float A = aff[r] + bbv;
        float uu = uv[r].x, vv = uv[r].y;
        // cls0: vv>=0 && uu>=0 -> +A ; cls2: uu<0 && uu<vv -> -A ; else 0
        float s = (uu >= 0.0f && vv >= 0.0f) ? A
                : ((uu < 0.0f && uu < vv) ? -A : 0.0f);
        if (i == j) s = 0.0f;
        out[i * N_GENES + j] = s;
    }
}

extern "C" void kernel_launch(void* const* d_in, const int* in_sizes, int n_in,
                              void* d_out, int out_size, void* d_ws, size_t ws_size,
                              hipStream_t stream)
{
    const float* X  = (const float*)d_in[0];  // [768,128]
    const float* W1 = (const float*)d_in[1];  // [128,256]
    const float* b1 = (const float*)d_in[2];  // [128]
    const float* W2 = (const float*)d_in[3];  // [3,128]
    const float* b2 = (const float*)d_in[4];  // [3]
    const float* Wb = (const float*)d_in[5];  // [1,128,128]
    const float* bb = (const float*)d_in[6];  // [1]
    float* out = (float*)d_out;

    float* ws = (float*)d_ws;
    float*    AiB = ws;                               // 768*128 f32
    float*    Bjp = ws + N_GENES * H;                 // 768*128 f32
    float*    Wd  = ws + 2 * N_GENES * H;             // 256 f32, {u,v} interleaved
    _Float16* Yh  = (_Float16*)(ws + 2 * N_GENES * H + 256);   // 768*128 f16
    _Float16* Xh  = Yh + N_GENES * H;                           // 768*128 f16

    grn_pre <<<N_GENES / 3, 128, 0, stream>>>(X, W1, b1, Wb, W2, AiB, Bjp, Wd, Yh, Xh);
    grn_main<<<16 * 48,     256, 0, stream>>>(AiB, Bjp, Yh, Xh, Wd, b2, bb, out);
}